// Round 9
// baseline (103.936 us; speedup 1.0000x reference)
//
#include <hip/hip_runtime.h>
#include <math.h>

#define TWO_PI_F 6.283185307179586f
#define ROWS 1024          // rows per tile (12 KB LDS per buffer)
#define BLK  256

typedef float f32x4 __attribute__((ext_vector_type(4)));
typedef int   i32x4 __attribute__((ext_vector_type(4)));

// Kernel A: per-group rotation matrices, padded to 12 floats/group
// (rows at float4 offsets 0,1,2). R = I + sin*K + (1-cos)*K^2; identity if
// apply_rand >= 0.5.
__global__ void compute_R_kernel(const float* __restrict__ axis,
                                 const float* __restrict__ angle,
                                 const float* __restrict__ apply_rand,
                                 float* __restrict__ R, int G) {
    int g = blockIdx.x * blockDim.x + threadIdx.x;
    if (g >= G) return;
    float a = axis[3 * g + 0];
    float b = axis[3 * g + 1];
    float c = axis[3 * g + 2];
    float inv = rsqrtf(a * a + b * b + c * c);
    a *= inv; b *= inv; c *= inv;
    float th = angle[g] * TWO_PI_F;
    float s, co;
    sincosf(th, &s, &co);
    float omc = 1.0f - co;

    float r00 = 1.0f - omc * (b * b + c * c);
    float r01 = -s * c + omc * (a * b);
    float r02 =  s * b + omc * (a * c);
    float r10 =  s * c + omc * (a * b);
    float r11 = 1.0f - omc * (a * a + c * c);
    float r12 = -s * a + omc * (b * c);
    float r20 = -s * b + omc * (a * c);
    float r21 =  s * a + omc * (b * c);
    float r22 = 1.0f - omc * (a * a + b * b);

    if (!(apply_rand[g] < 0.5f)) {
        r00 = 1.0f; r01 = 0.0f; r02 = 0.0f;
        r10 = 0.0f; r11 = 1.0f; r12 = 0.0f;
        r20 = 0.0f; r21 = 0.0f; r22 = 1.0f;
    }
    float4* Rg = reinterpret_cast<float4*>(R + 12 * (size_t)g);
    Rg[0] = make_float4(r00, r01, r02, 0.0f);
    Rg[1] = make_float4(r10, r11, r12, 0.0f);
    Rg[2] = make_float4(r20, r21, r22, 0.0f);
}

// Rotate the rows staged in bufLds (rows block-uniform), 4 rows/thread,
// in place. bi holds the 4 batch indices for this thread's rows.
template <bool HAS_BATCH>
__device__ __forceinline__ void rotate_tile(float* bufLds, int4 bi,
                                            const float* __restrict__ R,
                                            const int* __restrict__ batch,
                                            size_t rowBase, int rows, int tid) {
    float4* buf4 = reinterpret_cast<float4*>(bufLds);
    const int nRow4 = rows >> 2;
    if (tid < nRow4) {
        float4 p0 = buf4[3 * tid + 0];
        float4 p1 = buf4[3 * tid + 1];
        float4 p2 = buf4[3 * tid + 2];
        float rowsv[4][3] = {
            {p0.x, p0.y, p0.z},
            {p0.w, p1.x, p1.y},
            {p1.z, p1.w, p2.x},
            {p2.y, p2.z, p2.w}};
        int gs[4] = {bi.x, bi.y, bi.z, bi.w};
        float oo[12];
#pragma unroll
        for (int r = 0; r < 4; ++r) {
            const float4* Rg = reinterpret_cast<const float4*>(R + 12 * (size_t)gs[r]);
            float4 R0 = Rg[0];
            float4 R1 = Rg[1];
            float4 R2 = Rg[2];
            float v0 = rowsv[r][0], v1 = rowsv[r][1], v2 = rowsv[r][2];
            oo[3 * r + 0] = R0.x * v0 + R0.y * v1 + R0.z * v2;
            oo[3 * r + 1] = R1.x * v0 + R1.y * v1 + R1.z * v2;
            oo[3 * r + 2] = R2.x * v0 + R2.y * v1 + R2.z * v2;
        }
        buf4[3 * tid + 0] = make_float4(oo[0], oo[1], oo[2], oo[3]);
        buf4[3 * tid + 1] = make_float4(oo[4], oo[5], oo[6], oo[7]);
        buf4[3 * tid + 2] = make_float4(oo[8], oo[9], oo[10], oo[11]);
    } else if (tid == nRow4 && (rows & 3)) {
        // scalar tail rows — not hit for these sizes, kept for safety
        for (int r = nRow4 * 4; r < rows; ++r) {
            size_t row = rowBase + r;
            int g = HAS_BATCH ? batch[row] : (int)row;
            const float* Rg = R + 12 * (size_t)g;
            float v0 = bufLds[3 * r + 0], v1 = bufLds[3 * r + 1], v2 = bufLds[3 * r + 2];
            float t0 = Rg[0] * v0 + Rg[1] * v1 + Rg[2]  * v2;
            float t1 = Rg[4] * v0 + Rg[5] * v1 + Rg[6]  * v2;
            float t2 = Rg[8] * v0 + Rg[9] * v1 + Rg[10] * v2;
            bufLds[3 * r + 0] = t0; bufLds[3 * r + 1] = t1; bufLds[3 * r + 2] = t2;
        }
    }
}

// NT store of a tile from LDS to global.
__device__ __forceinline__ void store_tile_nt(const float* bufLds,
                                              float* __restrict__ out,
                                              size_t rowBase, int rows, int tid) {
    const int floatsHere = rows * 3;
    const int f4Here = floatsHere >> 2;
    const int tailFloats = floatsHere & 3;
    const f32x4* b4 = reinterpret_cast<const f32x4*>(bufLds);
    f32x4* dst = reinterpret_cast<f32x4*>(out + rowBase * 3);
    if (tid < f4Here) {
        f32x4 val = b4[tid];
        __builtin_nontemporal_store(val, &dst[tid]);
    }
    if (tid + 256 < f4Here) {
        f32x4 val = b4[tid + 256];
        __builtin_nontemporal_store(val, &dst[tid + 256]);
    }
    if (tid + 512 < f4Here) {
        f32x4 val = b4[tid + 512];
        __builtin_nontemporal_store(val, &dst[tid + 512]);
    }
    if (tailFloats && tid < tailFloats) {
        int fi = (f4Here << 2) + tid;
        __builtin_nontemporal_store(bufLds[fi], &out[rowBase * 3 + fi]);
    }
}

// Kernel B (2-tile pipelined): each block owns TWO adjacent 1024-row tiles.
// ALL global loads issued back-to-back at kernel start. Batch-index loads
// are NON-TEMPORAL (stream, zero intra-replay reuse, 72 MB) so the float
// inputs (216 MB) fit and stay resident in the 256 MB L3 across timed
// replays. Output stores non-temporal for the same reason.
template <bool HAS_BATCH>
__global__ __launch_bounds__(BLK) void apply_rot_lds2(
        const float* __restrict__ v,
        const int* __restrict__ batch,
        const float* __restrict__ R,
        float* __restrict__ out, int n) {
    __shared__ float buf[2][ROWS * 3];
    const int tid = threadIdx.x;

    size_t rb0 = (size_t)(blockIdx.x * 2) * ROWS;
    size_t rb1 = rb0 + ROWS;
    int rows0 = n - (int)rb0; rows0 = rows0 < 0 ? 0 : (rows0 > ROWS ? ROWS : rows0);
    int rows1 = n - (int)rb1; rows1 = rows1 < 0 ? 0 : (rows1 > ROWS ? ROWS : rows1);

    // ---- issue ALL global loads upfront (T14 issue-early) ----
    float4 p00 = make_float4(0, 0, 0, 0), p01 = p00, p02 = p00;
    float4 p10 = p00, p11 = p00, p12 = p00;
    float t0f = 0.f, t1f = 0.f;
    int4 bi0 = make_int4(0, 0, 0, 0), bi1 = bi0;
    {
        const float4* src0 = reinterpret_cast<const float4*>(v + rb0 * 3);
        int f40 = (rows0 * 3) >> 2;
        if (tid < f40)       p00 = src0[tid];
        if (tid + 256 < f40) p01 = src0[tid + 256];
        if (tid + 512 < f40) p02 = src0[tid + 512];
        int tf0 = (rows0 * 3) & 3;
        if (tf0 && tid < tf0) t0f = v[rb0 * 3 + (((size_t)f40) << 2) + tid];
    }
    if (rows1 > 0) {
        const float4* src1 = reinterpret_cast<const float4*>(v + rb1 * 3);
        int f41 = (rows1 * 3) >> 2;
        if (tid < f41)       p10 = src1[tid];
        if (tid + 256 < f41) p11 = src1[tid + 256];
        if (tid + 512 < f41) p12 = src1[tid + 512];
        int tf1 = (rows1 * 3) & 3;
        if (tf1 && tid < tf1) t1f = v[rb1 * 3 + (((size_t)f41) << 2) + tid];
    }
    if (tid < (rows0 >> 2)) {
        if (HAS_BATCH) {
            i32x4 t = __builtin_nontemporal_load(
                reinterpret_cast<const i32x4*>(batch + rb0) + tid);
            bi0 = make_int4(t.x, t.y, t.z, t.w);
        } else {
            int b = (int)rb0 + 4 * tid; bi0 = make_int4(b, b + 1, b + 2, b + 3);
        }
    }
    if (rows1 > 0 && tid < (rows1 >> 2)) {
        if (HAS_BATCH) {
            i32x4 t = __builtin_nontemporal_load(
                reinterpret_cast<const i32x4*>(batch + rb1) + tid);
            bi1 = make_int4(t.x, t.y, t.z, t.w);
        } else {
            int b = (int)rb1 + 4 * tid; bi1 = make_int4(b, b + 1, b + 2, b + 3);
        }
    }

    // ---- stage tile 0 ----
    {
        float4* b4 = reinterpret_cast<float4*>(buf[0]);
        int f40 = (rows0 * 3) >> 2;
        if (tid < f40)       b4[tid]       = p00;
        if (tid + 256 < f40) b4[tid + 256] = p01;
        if (tid + 512 < f40) b4[tid + 512] = p02;
        int tf0 = (rows0 * 3) & 3;
        if (tf0 && tid < tf0) buf[0][(f40 << 2) + tid] = t0f;
    }
    __syncthreads();

    rotate_tile<HAS_BATCH>(buf[0], bi0, R, batch, rb0, rows0, tid);
    __syncthreads();

    // ---- stage tile 1 into the other buffer, then store tile 0 ----
    if (rows1 > 0) {
        float4* b4 = reinterpret_cast<float4*>(buf[1]);
        int f41 = (rows1 * 3) >> 2;
        if (tid < f41)       b4[tid]       = p10;
        if (tid + 256 < f41) b4[tid + 256] = p11;
        if (tid + 512 < f41) b4[tid + 512] = p12;
        int tf1 = (rows1 * 3) & 3;
        if (tf1 && tid < tf1) buf[1][(f41 << 2) + tid] = t1f;
    }
    store_tile_nt(buf[0], out, rb0, rows0, tid);

    if (rows1 > 0) {
        __syncthreads();
        rotate_tile<HAS_BATCH>(buf[1], bi1, R, batch, rb1, rows1, tid);
        __syncthreads();
        store_tile_nt(buf[1], out, rb1, rows1, tid);
    }
}

extern "C" void kernel_launch(void* const* d_in, const int* in_sizes, int n_in,
                              void* d_out, int out_size, void* d_ws, size_t ws_size,
                              hipStream_t stream) {
    const float* x          = (const float*)d_in[0];
    const float* edge_attr  = (const float*)d_in[1];
    const float* y          = (const float*)d_in[2];
    const int*   node_batch = (const int*)d_in[3];
    const int*   edge_batch = (const int*)d_in[4];
    const float* axis       = (const float*)d_in[5];
    const float* angle      = (const float*)d_in[6];
    const float* apply_rand = (const float*)d_in[7];

    const int N = in_sizes[3];
    const int E = in_sizes[4];
    const int G = in_sizes[6];

    float* R = (float*)d_ws;        // G*12 floats = 384 KB
    float* x_out = (float*)d_out;
    float* e_out = x_out + 3 * (size_t)N;
    float* y_out = e_out + 3 * (size_t)E;

    compute_R_kernel<<<(G + BLK - 1) / BLK, BLK, 0, stream>>>(
        axis, angle, apply_rand, R, G);

    // two tiles per block
    int nbE = (int)(((size_t)E + 2 * ROWS - 1) / (2 * ROWS));
    int nbN = (int)(((size_t)N + 2 * ROWS - 1) / (2 * ROWS));
    int nbG = (int)(((size_t)G + 2 * ROWS - 1) / (2 * ROWS));

    apply_rot_lds2<true><<<nbE, BLK, 0, stream>>>(edge_attr, edge_batch, R, e_out, E);
    apply_rot_lds2<true><<<nbN, BLK, 0, stream>>>(x, node_batch, R, x_out, N);
    apply_rot_lds2<false><<<nbG, BLK, 0, stream>>>(y, nullptr, R, y_out, G);
}

// Round 10
// 97.268 us; speedup vs baseline: 1.0686x; 1.0686x over previous
//
#include <hip/hip_runtime.h>
#include <math.h>

#define TWO_PI_F 6.283185307179586f
#define WROWS 256          // rows per wave-tile (3 KB LDS)
#define WBLK  64           // one wave per block

typedef float f32x4 __attribute__((ext_vector_type(4)));

// Kernel A: per-group rotation matrices, padded to 12 floats/group
// (rows at float4 offsets 0,1,2). R = I + sin*K + (1-cos)*K^2; identity if
// apply_rand >= 0.5.
__global__ void compute_R_kernel(const float* __restrict__ axis,
                                 const float* __restrict__ angle,
                                 const float* __restrict__ apply_rand,
                                 float* __restrict__ R, int G) {
    int g = blockIdx.x * blockDim.x + threadIdx.x;
    if (g >= G) return;
    float a = axis[3 * g + 0];
    float b = axis[3 * g + 1];
    float c = axis[3 * g + 2];
    float inv = rsqrtf(a * a + b * b + c * c);
    a *= inv; b *= inv; c *= inv;
    float th = angle[g] * TWO_PI_F;
    float s, co;
    sincosf(th, &s, &co);
    float omc = 1.0f - co;

    float r00 = 1.0f - omc * (b * b + c * c);
    float r01 = -s * c + omc * (a * b);
    float r02 =  s * b + omc * (a * c);
    float r10 =  s * c + omc * (a * b);
    float r11 = 1.0f - omc * (a * a + c * c);
    float r12 = -s * a + omc * (b * c);
    float r20 = -s * b + omc * (a * c);
    float r21 =  s * a + omc * (b * c);
    float r22 = 1.0f - omc * (a * a + b * b);

    if (!(apply_rand[g] < 0.5f)) {
        r00 = 1.0f; r01 = 0.0f; r02 = 0.0f;
        r10 = 0.0f; r11 = 1.0f; r12 = 0.0f;
        r20 = 0.0f; r21 = 0.0f; r22 = 1.0f;
    }
    float4* Rg = reinterpret_cast<float4*>(R + 12 * (size_t)g);
    Rg[0] = make_float4(r00, r01, r02, 0.0f);
    Rg[1] = make_float4(r10, r11, r12, 0.0f);
    Rg[2] = make_float4(r20, r21, r22, 0.0f);
}

// Kernel B (wave-tile): ONE WAVE per block, 256 rows per wave (192 float4,
// 3 KB LDS). No inter-wave barriers anywhere -> no convoying; up to 32
// independent waves/CU continuously issuing memory ops. Same LDS AoS-3
// shuffle as before; NT stores keep outputs from evicting inputs in L3.
template <bool HAS_BATCH>
__global__ __launch_bounds__(WBLK) void apply_rot_wave(
        const float* __restrict__ v,
        const int* __restrict__ batch,
        const float* __restrict__ R,
        float* __restrict__ out, int n) {
    __shared__ float buf[WROWS * 3];
    float4* buf4 = reinterpret_cast<float4*>(buf);

    const int lane = threadIdx.x;
    const size_t rowBase = (size_t)blockIdx.x * WROWS;
    int rows = n - (int)rowBase;
    if (rows > WROWS) rows = WROWS;
    const int floatsHere = rows * 3;
    const int f4Here = floatsHere >> 2;       // 192 for a full tile
    const int tailFloats = floatsHere & 3;
    const int nRow4 = rows >> 2;              // 64 for a full tile

    // ---- issue all global loads ----
    float4 a0 = make_float4(0, 0, 0, 0), a1 = a0, a2 = a0;
    float aT = 0.f;
    {
        const float4* src = reinterpret_cast<const float4*>(v + rowBase * 3);
        if (lane < f4Here)       a0 = src[lane];
        if (lane + 64 < f4Here)  a1 = src[lane + 64];
        if (lane + 128 < f4Here) a2 = src[lane + 128];
        if (tailFloats && lane < tailFloats)
            aT = v[rowBase * 3 + (((size_t)f4Here) << 2) + lane];
    }
    int4 bi = make_int4(0, 0, 0, 0);
    if (lane < nRow4) {
        if (HAS_BATCH) {
            bi = *(reinterpret_cast<const int4*>(batch + rowBase) + lane);
        } else {
            int b = (int)rowBase + 4 * lane;
            bi = make_int4(b, b + 1, b + 2, b + 3);
        }
    }

    // ---- stage into LDS (single wave: __syncthreads is just a waitcnt) ----
    if (lane < f4Here)       buf4[lane]       = a0;
    if (lane + 64 < f4Here)  buf4[lane + 64]  = a1;
    if (lane + 128 < f4Here) buf4[lane + 128] = a2;
    if (tailFloats && lane < tailFloats) buf[(f4Here << 2) + lane] = aT;
    __syncthreads();

    // ---- rotate 4 rows per lane, in place ----
    if (lane < nRow4) {
        float4 p0 = buf4[3 * lane + 0];
        float4 p1 = buf4[3 * lane + 1];
        float4 p2 = buf4[3 * lane + 2];
        float rowsv[4][3] = {
            {p0.x, p0.y, p0.z},
            {p0.w, p1.x, p1.y},
            {p1.z, p1.w, p2.x},
            {p2.y, p2.z, p2.w}};
        int gs[4] = {bi.x, bi.y, bi.z, bi.w};
        float oo[12];
#pragma unroll
        for (int r = 0; r < 4; ++r) {
            const float4* Rg = reinterpret_cast<const float4*>(R + 12 * (size_t)gs[r]);
            float4 R0 = Rg[0];
            float4 R1 = Rg[1];
            float4 R2 = Rg[2];
            float v0 = rowsv[r][0], v1 = rowsv[r][1], v2 = rowsv[r][2];
            oo[3 * r + 0] = R0.x * v0 + R0.y * v1 + R0.z * v2;
            oo[3 * r + 1] = R1.x * v0 + R1.y * v1 + R1.z * v2;
            oo[3 * r + 2] = R2.x * v0 + R2.y * v1 + R2.z * v2;
        }
        buf4[3 * lane + 0] = make_float4(oo[0], oo[1], oo[2], oo[3]);
        buf4[3 * lane + 1] = make_float4(oo[4], oo[5], oo[6], oo[7]);
        buf4[3 * lane + 2] = make_float4(oo[8], oo[9], oo[10], oo[11]);
    } else if (lane == nRow4 && (rows & 3)) {
        // scalar tail rows — not hit for these sizes, kept for safety
        for (int r = nRow4 * 4; r < rows; ++r) {
            size_t row = rowBase + r;
            int g = HAS_BATCH ? batch[row] : (int)row;
            const float* Rg = R + 12 * (size_t)g;
            float v0 = buf[3 * r + 0], v1 = buf[3 * r + 1], v2 = buf[3 * r + 2];
            float t0 = Rg[0] * v0 + Rg[1] * v1 + Rg[2]  * v2;
            float t1 = Rg[4] * v0 + Rg[5] * v1 + Rg[6]  * v2;
            float t2 = Rg[8] * v0 + Rg[9] * v1 + Rg[10] * v2;
            buf[3 * r + 0] = t0; buf[3 * r + 1] = t1; buf[3 * r + 2] = t2;
        }
    }
    __syncthreads();

    // ---- NT store out ----
    {
        const f32x4* b4 = reinterpret_cast<const f32x4*>(buf);
        f32x4* dst = reinterpret_cast<f32x4*>(out + rowBase * 3);
        if (lane < f4Here) {
            f32x4 val = b4[lane];
            __builtin_nontemporal_store(val, &dst[lane]);
        }
        if (lane + 64 < f4Here) {
            f32x4 val = b4[lane + 64];
            __builtin_nontemporal_store(val, &dst[lane + 64]);
        }
        if (lane + 128 < f4Here) {
            f32x4 val = b4[lane + 128];
            __builtin_nontemporal_store(val, &dst[lane + 128]);
        }
        if (tailFloats && lane < tailFloats) {
            int fi = (f4Here << 2) + lane;
            __builtin_nontemporal_store(buf[fi], &out[rowBase * 3 + fi]);
        }
    }
}

extern "C" void kernel_launch(void* const* d_in, const int* in_sizes, int n_in,
                              void* d_out, int out_size, void* d_ws, size_t ws_size,
                              hipStream_t stream) {
    const float* x          = (const float*)d_in[0];
    const float* edge_attr  = (const float*)d_in[1];
    const float* y          = (const float*)d_in[2];
    const int*   node_batch = (const int*)d_in[3];
    const int*   edge_batch = (const int*)d_in[4];
    const float* axis       = (const float*)d_in[5];
    const float* angle      = (const float*)d_in[6];
    const float* apply_rand = (const float*)d_in[7];

    const int N = in_sizes[3];
    const int E = in_sizes[4];
    const int G = in_sizes[6];

    float* R = (float*)d_ws;        // G*12 floats = 384 KB
    float* x_out = (float*)d_out;
    float* e_out = x_out + 3 * (size_t)N;
    float* y_out = e_out + 3 * (size_t)E;

    compute_R_kernel<<<(G + 255) / 256, 256, 0, stream>>>(
        axis, angle, apply_rand, R, G);

    int nbE = (int)(((size_t)E + WROWS - 1) / WROWS);
    int nbN = (int)(((size_t)N + WROWS - 1) / WROWS);
    int nbG = (int)(((size_t)G + WROWS - 1) / WROWS);

    apply_rot_wave<true><<<nbE, WBLK, 0, stream>>>(edge_attr, edge_batch, R, e_out, E);
    apply_rot_wave<true><<<nbN, WBLK, 0, stream>>>(x, node_batch, R, x_out, N);
    apply_rot_wave<false><<<nbG, WBLK, 0, stream>>>(y, nullptr, R, y_out, G);
}

// Round 11
// 94.193 us; speedup vs baseline: 1.1034x; 1.0326x over previous
//
#include <hip/hip_runtime.h>
#include <math.h>

#define TWO_PI_F 6.283185307179586f
#define WROWS 256          // rows per wave-tile (3 KB LDS)
#define WBLK  64           // one wave per block

typedef float f32x4 __attribute__((ext_vector_type(4)));

// Kernel A: per-group rotation matrices, padded to 12 floats/group
// (rows at float4 offsets 0,1,2). R = I + sin*K + (1-cos)*K^2; identity if
// apply_rand >= 0.5.
__global__ void compute_R_kernel(const float* __restrict__ axis,
                                 const float* __restrict__ angle,
                                 const float* __restrict__ apply_rand,
                                 float* __restrict__ R, int G) {
    int g = blockIdx.x * blockDim.x + threadIdx.x;
    if (g >= G) return;
    float a = axis[3 * g + 0];
    float b = axis[3 * g + 1];
    float c = axis[3 * g + 2];
    float inv = rsqrtf(a * a + b * b + c * c);
    a *= inv; b *= inv; c *= inv;
    float th = angle[g] * TWO_PI_F;
    float s, co;
    sincosf(th, &s, &co);
    float omc = 1.0f - co;

    float r00 = 1.0f - omc * (b * b + c * c);
    float r01 = -s * c + omc * (a * b);
    float r02 =  s * b + omc * (a * c);
    float r10 =  s * c + omc * (a * b);
    float r11 = 1.0f - omc * (a * a + c * c);
    float r12 = -s * a + omc * (b * c);
    float r20 = -s * b + omc * (a * c);
    float r21 =  s * a + omc * (b * c);
    float r22 = 1.0f - omc * (a * a + b * b);

    if (!(apply_rand[g] < 0.5f)) {
        r00 = 1.0f; r01 = 0.0f; r02 = 0.0f;
        r10 = 0.0f; r11 = 1.0f; r12 = 0.0f;
        r20 = 0.0f; r21 = 0.0f; r22 = 1.0f;
    }
    float4* Rg = reinterpret_cast<float4*>(R + 12 * (size_t)g);
    Rg[0] = make_float4(r00, r01, r02, 0.0f);
    Rg[1] = make_float4(r10, r11, r12, 0.0f);
    Rg[2] = make_float4(r20, r21, r22, 0.0f);
}

// Kernel A2: group boundaries from the SORTED batch arrays.
// start[g] = lower_bound(batch, g)  (first row with batch >= g), start[G]=n.
// One launch covers both arrays: i in [0,G] -> node, i in [G+1, 2G+1] -> edge.
__global__ void bounds_kernel(const int* __restrict__ nb, int N,
                              const int* __restrict__ eb, int E, int G,
                              int* __restrict__ nstart,
                              int* __restrict__ estart) {
    int i = blockIdx.x * blockDim.x + threadIdx.x;
    if (i >= 2 * (G + 1)) return;
    bool isEdge = i > G;
    int g = isEdge ? i - (G + 1) : i;
    const int* b = isEdge ? eb : nb;
    int n = isEdge ? E : N;
    int lo = 0, hi = n;
    while (lo < hi) {
        int mid = (lo + hi) >> 1;
        if (b[mid] < g) lo = mid + 1; else hi = mid;
    }
    if (isEdge) estart[g] = lo; else nstart[g] = lo;
}

// Kernel B (wave-tile): ONE WAVE per block, 256 rows per wave (192 float4,
// 3 KB LDS). Group indices are DERIVED from the 32 KB boundaries array
// (L1/L2-resident) instead of streaming 72 MB of batch indices from HBM:
// binary search for the tile's first group (13 broadcast loads, overlapped
// with the input-load latency), then per-lane linear advance over its 4
// consecutive rows. NT stores keep outputs from evicting inputs in L3.
template <bool HAS_BATCH>
__global__ __launch_bounds__(WBLK) void apply_rot_wave(
        const float* __restrict__ v,
        const int* __restrict__ start,   // G+1 boundaries (HAS_BATCH only)
        const float* __restrict__ R,
        float* __restrict__ out, int n, int G) {
    __shared__ float buf[WROWS * 3];
    float4* buf4 = reinterpret_cast<float4*>(buf);

    const int lane = threadIdx.x;
    const size_t rowBase = (size_t)blockIdx.x * WROWS;
    int rows = n - (int)rowBase;
    if (rows > WROWS) rows = WROWS;
    const int floatsHere = rows * 3;
    const int f4Here = floatsHere >> 2;       // 192 for a full tile
    const int tailFloats = floatsHere & 3;
    const int nRow4 = rows >> 2;              // 64 for a full tile

    // ---- issue the input loads first (longest latency) ----
    float4 a0 = make_float4(0, 0, 0, 0), a1 = a0, a2 = a0;
    float aT = 0.f;
    {
        const float4* src = reinterpret_cast<const float4*>(v + rowBase * 3);
        if (lane < f4Here)       a0 = src[lane];
        if (lane + 64 < f4Here)  a1 = src[lane + 64];
        if (lane + 128 < f4Here) a2 = src[lane + 128];
        if (tailFloats && lane < tailFloats)
            aT = v[rowBase * 3 + (((size_t)f4Here) << 2) + lane];
    }

    // ---- group indices from boundaries (overlaps the loads above) ----
    int gs[4];
    int gTail = 0;
    if (HAS_BATCH) {
        // all lanes run the same search: broadcast loads, no divergence
        int rb = (int)rowBase;
        int lo = 0, hi = G;
        while (lo < hi) {                     // max g with start[g] <= rb
            int mid = (lo + hi + 1) >> 1;
            if (start[mid] <= rb) lo = mid; else hi = mid - 1;
        }
        int g = lo;
        gTail = g;
        if (lane < nRow4) {
            int row0 = rb + 4 * lane;
#pragma unroll
            for (int r = 0; r < 4; ++r) {
                int row = row0 + r;
                while (start[g + 1] <= row) ++g;   // ~1-4 groups per tile
                gs[r] = g;
            }
        }
    } else {
        int b = (int)rowBase + 4 * lane;
        gs[0] = b; gs[1] = b + 1; gs[2] = b + 2; gs[3] = b + 3;
    }

    // ---- stage into LDS (single wave: barrier is just a waitcnt) ----
    if (lane < f4Here)       buf4[lane]       = a0;
    if (lane + 64 < f4Here)  buf4[lane + 64]  = a1;
    if (lane + 128 < f4Here) buf4[lane + 128] = a2;
    if (tailFloats && lane < tailFloats) buf[(f4Here << 2) + lane] = aT;
    __syncthreads();

    // ---- rotate 4 rows per lane, in place ----
    if (lane < nRow4) {
        float4 p0 = buf4[3 * lane + 0];
        float4 p1 = buf4[3 * lane + 1];
        float4 p2 = buf4[3 * lane + 2];
        float rowsv[4][3] = {
            {p0.x, p0.y, p0.z},
            {p0.w, p1.x, p1.y},
            {p1.z, p1.w, p2.x},
            {p2.y, p2.z, p2.w}};
        float oo[12];
#pragma unroll
        for (int r = 0; r < 4; ++r) {
            const float4* Rg = reinterpret_cast<const float4*>(R + 12 * (size_t)gs[r]);
            float4 R0 = Rg[0];
            float4 R1 = Rg[1];
            float4 R2 = Rg[2];
            float v0 = rowsv[r][0], v1 = rowsv[r][1], v2 = rowsv[r][2];
            oo[3 * r + 0] = R0.x * v0 + R0.y * v1 + R0.z * v2;
            oo[3 * r + 1] = R1.x * v0 + R1.y * v1 + R1.z * v2;
            oo[3 * r + 2] = R2.x * v0 + R2.y * v1 + R2.z * v2;
        }
        buf4[3 * lane + 0] = make_float4(oo[0], oo[1], oo[2], oo[3]);
        buf4[3 * lane + 1] = make_float4(oo[4], oo[5], oo[6], oo[7]);
        buf4[3 * lane + 2] = make_float4(oo[8], oo[9], oo[10], oo[11]);
    } else if (lane == nRow4 && (rows & 3)) {
        // scalar tail rows — not hit for these sizes, kept for safety
        int g = gTail;
        for (int r = nRow4 * 4; r < rows; ++r) {
            int row = (int)rowBase + r;
            if (HAS_BATCH) { while (start[g + 1] <= row) ++g; }
            else g = row;
            const float* Rg = R + 12 * (size_t)g;
            float v0 = buf[3 * r + 0], v1 = buf[3 * r + 1], v2 = buf[3 * r + 2];
            float t0 = Rg[0] * v0 + Rg[1] * v1 + Rg[2]  * v2;
            float t1 = Rg[4] * v0 + Rg[5] * v1 + Rg[6]  * v2;
            float t2 = Rg[8] * v0 + Rg[9] * v1 + Rg[10] * v2;
            buf[3 * r + 0] = t0; buf[3 * r + 1] = t1; buf[3 * r + 2] = t2;
        }
    }
    __syncthreads();

    // ---- NT store out ----
    {
        const f32x4* b4 = reinterpret_cast<const f32x4*>(buf);
        f32x4* dst = reinterpret_cast<f32x4*>(out + rowBase * 3);
        if (lane < f4Here) {
            f32x4 val = b4[lane];
            __builtin_nontemporal_store(val, &dst[lane]);
        }
        if (lane + 64 < f4Here) {
            f32x4 val = b4[lane + 64];
            __builtin_nontemporal_store(val, &dst[lane + 64]);
        }
        if (lane + 128 < f4Here) {
            f32x4 val = b4[lane + 128];
            __builtin_nontemporal_store(val, &dst[lane + 128]);
        }
        if (tailFloats && lane < tailFloats) {
            int fi = (f4Here << 2) + lane;
            __builtin_nontemporal_store(buf[fi], &out[rowBase * 3 + fi]);
        }
    }
}

extern "C" void kernel_launch(void* const* d_in, const int* in_sizes, int n_in,
                              void* d_out, int out_size, void* d_ws, size_t ws_size,
                              hipStream_t stream) {
    const float* x          = (const float*)d_in[0];
    const float* edge_attr  = (const float*)d_in[1];
    const float* y          = (const float*)d_in[2];
    const int*   node_batch = (const int*)d_in[3];
    const int*   edge_batch = (const int*)d_in[4];
    const float* axis       = (const float*)d_in[5];
    const float* angle      = (const float*)d_in[6];
    const float* apply_rand = (const float*)d_in[7];

    const int N = in_sizes[3];
    const int E = in_sizes[4];
    const int G = in_sizes[6];

    float* R = (float*)d_ws;                       // G*12 floats = 384 KB
    int* nstart = (int*)(R + 12 * (size_t)G);      // G+1 ints
    int* estart = nstart + (G + 1);                // G+1 ints
    float* x_out = (float*)d_out;
    float* e_out = x_out + 3 * (size_t)N;
    float* y_out = e_out + 3 * (size_t)E;

    compute_R_kernel<<<(G + 255) / 256, 256, 0, stream>>>(
        axis, angle, apply_rand, R, G);
    bounds_kernel<<<(2 * (G + 1) + 255) / 256, 256, 0, stream>>>(
        node_batch, N, edge_batch, E, G, nstart, estart);

    int nbE = (int)(((size_t)E + WROWS - 1) / WROWS);
    int nbN = (int)(((size_t)N + WROWS - 1) / WROWS);
    int nbG = (int)(((size_t)G + WROWS - 1) / WROWS);

    apply_rot_wave<true><<<nbE, WBLK, 0, stream>>>(edge_attr, estart, R, e_out, E, G);
    apply_rot_wave<true><<<nbN, WBLK, 0, stream>>>(x, nstart, R, x_out, N, G);
    apply_rot_wave<false><<<nbG, WBLK, 0, stream>>>(y, nullptr, R, y_out, G, G);
}